// Round 8
// baseline (1636.227 us; speedup 1.0000x reference)
//
#include <hip/hip_runtime.h>
#include <math.h>
#include <stdint.h>

#define BB 4
#define NN 1024
#define CC 768
#define HH 12
#define DH 64
#define KTOP 16

// ---------------- Kernel 1: fused QKV projection (fp32) ----------------
// out[m][col] = sum_c x[m][c]*w[col][c] + bias[col], col in [0,2304); scatter q/k/v fp32.
__global__ __launch_bounds__(256) void qkv_proj32(
    const float* __restrict__ x, const float* __restrict__ w,
    const float* __restrict__ bias,
    float* __restrict__ q32, float* __restrict__ k32, float* __restrict__ v32) {
    __shared__ float a_lds[64][17];
    __shared__ float b_lds[64][17];
    const int tid = threadIdx.x;
    const int m0 = blockIdx.x * 64, n0 = blockIdx.y * 64;   // n0 in [0,2304)
    const int ty = tid >> 4, tx = tid & 15;
    const int lr = tid >> 2, lc = (tid & 3) << 2;

    float acc[4][4];
#pragma unroll
    for (int i = 0; i < 4; ++i)
#pragma unroll
        for (int j = 0; j < 4; ++j) acc[i][j] = 0.0f;

    for (int k0 = 0; k0 < CC; k0 += 16) {
        float4 av = *reinterpret_cast<const float4*>(&x[(size_t)(m0 + lr) * CC + k0 + lc]);
        float4 wv = *reinterpret_cast<const float4*>(&w[(size_t)(n0 + lr) * CC + k0 + lc]);
        __syncthreads();
        a_lds[lr][lc + 0] = av.x; a_lds[lr][lc + 1] = av.y;
        a_lds[lr][lc + 2] = av.z; a_lds[lr][lc + 3] = av.w;
        b_lds[lr][lc + 0] = wv.x; b_lds[lr][lc + 1] = wv.y;
        b_lds[lr][lc + 2] = wv.z; b_lds[lr][lc + 3] = wv.w;
        __syncthreads();
#pragma unroll
        for (int kk = 0; kk < 16; ++kk) {
            float a0 = a_lds[ty + 0][kk];
            float a1 = a_lds[ty + 16][kk];
            float a2 = a_lds[ty + 32][kk];
            float a3 = a_lds[ty + 48][kk];
            float w0 = b_lds[tx + 0][kk];
            float w1 = b_lds[tx + 16][kk];
            float w2 = b_lds[tx + 32][kk];
            float w3 = b_lds[tx + 48][kk];
            acc[0][0] = fmaf(a0, w0, acc[0][0]); acc[0][1] = fmaf(a0, w1, acc[0][1]);
            acc[0][2] = fmaf(a0, w2, acc[0][2]); acc[0][3] = fmaf(a0, w3, acc[0][3]);
            acc[1][0] = fmaf(a1, w0, acc[1][0]); acc[1][1] = fmaf(a1, w1, acc[1][1]);
            acc[1][2] = fmaf(a1, w2, acc[1][2]); acc[1][3] = fmaf(a1, w3, acc[1][3]);
            acc[2][0] = fmaf(a2, w0, acc[2][0]); acc[2][1] = fmaf(a2, w1, acc[2][1]);
            acc[2][2] = fmaf(a2, w2, acc[2][2]); acc[2][3] = fmaf(a2, w3, acc[2][3]);
            acc[3][0] = fmaf(a3, w0, acc[3][0]); acc[3][1] = fmaf(a3, w1, acc[3][1]);
            acc[3][2] = fmaf(a3, w2, acc[3][2]); acc[3][3] = fmaf(a3, w3, acc[3][3]);
        }
    }

#pragma unroll
    for (int i = 0; i < 4; ++i) {
#pragma unroll
        for (int j = 0; j < 4; ++j) {
            int m = m0 + ty + i * 16;
            int col = n0 + tx + j * 16;              // [0,2304)
            float val = acc[i][j] + bias[col];
            int t = col / CC;
            int rem = col - t * CC;
            int h = rem >> 6, d = rem & 63;
            int b = m >> 10, n = m & 1023;
            size_t off = (((size_t)(b * HH + h)) * NN + n) * DH + d;
            if (t == 0) q32[off] = val;
            else if (t == 1) k32[off] = val;
            else v32[off] = val;
        }
    }
}

// ---------------- Kernel 2a: fp32 scores GEMM (64-row blocks) ----------------
__global__ __launch_bounds__(256) void scores32(
    const float* __restrict__ q32, const float* __restrict__ k32,
    float* __restrict__ attn_out) {
    __shared__ float qs[64][64];    // 16KB, swizzled float4 slots
    __shared__ float ks[128][64];   // 32KB
    const int bh = blockIdx.y;
    const int m0 = blockIdx.x * 64;
    const int tid = threadIdx.x;
    const int ty = tid >> 4, tx = tid & 15;

    const float* qb = q32 + ((size_t)bh * NN + m0) * DH;
    const float* kb = k32 + (size_t)bh * NN * DH;

    // stage q tile once (fold 0.125, swizzle): 1024 float4 slots
#pragma unroll
    for (int wv = 0; wv < 4; ++wv) {
        int e = tid + 256 * wv;             // 0..1023
        int row = e >> 4, d4 = e & 15;
        float4 f = *reinterpret_cast<const float4*>(&qb[(size_t)row * DH + d4 * 4]);
        f.x *= 0.125f; f.y *= 0.125f; f.z *= 0.125f; f.w *= 0.125f;
        ((float4*)qs[row])[d4 ^ (row >> 3)] = f;
    }

    float* orow0 = attn_out + ((size_t)bh * NN + m0) * NN;

    for (int c0 = 0; c0 < NN; c0 += 128) {
        __syncthreads();
#pragma unroll
        for (int wv = 0; wv < 8; ++wv) {
            int e = tid + 256 * wv;         // 0..2047
            int col = e >> 4, d4 = e & 15;
            float4 f = *reinterpret_cast<const float4*>(&kb[(size_t)(c0 + col) * DH + d4 * 4]);
            ((float4*)ks[col])[d4 ^ ((col >> 3) & 15)] = f;
        }
        __syncthreads();

        float acc[4][8];
#pragma unroll
        for (int i = 0; i < 4; ++i)
#pragma unroll
            for (int j = 0; j < 8; ++j) acc[i][j] = 0.0f;

#pragma unroll
        for (int d4 = 0; d4 < 16; ++d4) {
            float4 a4[4];
#pragma unroll
            for (int i = 0; i < 4; ++i)
                a4[i] = ((float4*)qs[4 * ty + i])[d4 ^ ((4 * ty + i) >> 3)];
#pragma unroll
            for (int j = 0; j < 8; ++j) {
                float4 b4 = ((float4*)ks[8 * tx + j])[d4 ^ tx];
#pragma unroll
                for (int i = 0; i < 4; ++i) {
                    acc[i][j] = fmaf(a4[i].x, b4.x, acc[i][j]);
                    acc[i][j] = fmaf(a4[i].y, b4.y, acc[i][j]);
                    acc[i][j] = fmaf(a4[i].z, b4.z, acc[i][j]);
                    acc[i][j] = fmaf(a4[i].w, b4.w, acc[i][j]);
                }
            }
        }

#pragma unroll
        for (int i = 0; i < 4; ++i) {
#pragma unroll
            for (int jj = 0; jj < 2; ++jj) {
                float4 o;
                o.x = acc[i][4 * jj + 0]; o.y = acc[i][4 * jj + 1];
                o.z = acc[i][4 * jj + 2]; o.w = acc[i][4 * jj + 3];
                *(float4*)&orow0[(size_t)(4 * ty + i) * NN + c0 + 8 * tx + 4 * jj] = o;
            }
        }
    }
}

// ---------------- Kernel 2b: bitonic top-16; slow path recomputes fp64 from x,W ----------
__device__ __forceinline__ uint32_t f2su(float f) {
    uint32_t u = __float_as_uint(f);
    return u ^ ((u & 0x80000000u) ? 0xFFFFFFFFu : 0x80000000u);
}
__device__ __forceinline__ float su2f(uint32_t s) {
    uint32_t u = s ^ ((s & 0x80000000u) ? 0x80000000u : 0xFFFFFFFFu);
    return __uint_as_float(u);
}

__global__ __launch_bounds__(256) void topk_select(
    const float* __restrict__ x, const float* __restrict__ w_in,
    const float* __restrict__ b_in, const float* __restrict__ v32,
    float* __restrict__ attn_out, float* __restrict__ xatt) {
    __shared__ int      cand_idx[4][64];
    __shared__ uint32_t cand_val[4][64];
    const int blk = blockIdx.x;
    const int wave = threadIdx.x >> 6, lane = threadIdx.x & 63;
    const int bh = blk >> 8;
    const int qn = ((blk & 255) << 2) | wave;

    float* srow = attn_out + ((size_t)bh * NN + qn) * NN;

    // load 16 scores, transform to order-preserving sortable uint
    uint32_t su[16];
#pragma unroll
    for (int i = 0; i < 4; ++i) {
        float4 t = *(const float4*)&srow[i * 256 + lane * 4];
        su[4 * i + 0] = f2su(t.x); su[4 * i + 1] = f2su(t.y);
        su[4 * i + 2] = f2su(t.z); su[4 * i + 3] = f2su(t.w);
    }

    // binary search MSB->LSB: largest thr with count(su >= thr) >= 17; early-exit in [17,64]
    uint32_t thr = 0;
    for (int b = 31; b >= 0; --b) {
        uint32_t test = thr | (1u << b);
        int cnt = 0;
#pragma unroll
        for (int r = 0; r < 16; ++r)
            cnt += __popcll(__ballot(su[r] >= test));
        if (cnt >= 17) { thr = test; if (cnt <= 64) break; }
    }

    // compact (value, column) candidates into LDS (column order)
    int C = 0;
#pragma unroll
    for (int r = 0; r < 16; ++r) {
        bool pr = (su[r] >= thr);
        unsigned long long mask = __ballot(pr);
        if (pr) {
            int pos = C + __popcll(mask & ((1ull << lane) - 1ull));
            if (pos < 64) {
                cand_idx[wave][pos] = ((r >> 2) << 8) + (lane << 2) + (r & 3);
                cand_val[wave][pos] = su[r];
            }
        }
        C += __popcll(mask);
    }
    if (C > 64) C = 64;

    uint32_t key = (lane < C) ? cand_val[wave][lane] : 0u;
    int      idx = (lane < C) ? cand_idx[wave][lane] : (0x40000000 + lane);

    // bitonic sort 64 lanes: (key desc, idx asc)  — 21 exchange steps
#pragma unroll
    for (int k = 2; k <= 64; k <<= 1) {
#pragma unroll
        for (int j = k >> 1; j > 0; j >>= 1) {
            uint32_t ok = __shfl_xor(key, j);
            int      oi = __shfl_xor(idx, j);
            bool mine_better = (key > ok) || (key == ok && idx < oi);
            bool lower = ((lane & j) == 0);
            bool dir_desc = ((lane & k) == 0);
            bool keep = dir_desc ? (lower ? mine_better : !mine_better)
                                 : (lower ? !mine_better : mine_better);
            if (!keep) { key = ok; idx = oi; }
        }
    }

    float f = su2f(key);                  // valid for lane < C (C >= 17)
    float f15 = __shfl(f, 15);
    float f16 = __shfl(f, 16);

    float p = 0.0f;
    int selIdx = idx;

    if (f15 - f16 > 2e-4f) {
        // ---- fast path: fp32 ordering provably matches fp64 at the 16/17 boundary ----
        float m = __shfl(f, 0);
        float e = (lane < KTOP) ? expf(f - m) : 0.0f;
        float sum = e;
#pragma unroll
        for (int off = 32; off; off >>= 1) sum += __shfl_xor(sum, off);
        p = e / sum;
    } else {
        // ---- slow path (~1% of rows): exact fp64 rescore recomputed from x, W ----
        uint32_t thr2 = f2su(f15 - 4e-4f);
        int C2 = 0;
#pragma unroll
        for (int r = 0; r < 16; ++r) {
            bool pr = (su[r] >= thr2);
            unsigned long long mask = __ballot(pr);
            if (pr) {
                int pos = C2 + __popcll(mask & ((1ull << lane) - 1ull));
                if (pos < 64) cand_idx[wave][pos] = ((r >> 2) << 8) + (lane << 2) + (r & 3);
            }
            C2 += __popcll(mask);
        }
        if (C2 > 64) C2 = 64;
        int cand = cand_idx[wave][lane < C2 ? lane : 0];

        const int bq = bh / HH, hq = bh - bq * HH;
        // q64[lane]: fp64 projection of query row, dim d = lane
        const float* xq = x + ((size_t)bq * NN + qn) * CC;
        const float* wq = w_in + (size_t)(hq * DH + lane) * CC;
        double qa0 = 0.0, qa1 = 0.0;
        for (int c = 0; c < CC; c += 8) {
            float4 a = *(const float4*)&xq[c];
            float4 b4 = *(const float4*)&wq[c];
            float4 a2 = *(const float4*)&xq[c + 4];
            float4 b2 = *(const float4*)&wq[c + 4];
            qa0 = fma((double)a.x, (double)b4.x, qa0);
            qa0 = fma((double)a.y, (double)b4.y, qa0);
            qa0 = fma((double)a.z, (double)b4.z, qa0);
            qa0 = fma((double)a.w, (double)b4.w, qa0);
            qa1 = fma((double)a2.x, (double)b2.x, qa1);
            qa1 = fma((double)a2.y, (double)b2.y, qa1);
            qa1 = fma((double)a2.z, (double)b2.z, qa1);
            qa1 = fma((double)a2.w, (double)b2.w, qa1);
        }
        const double qd = qa0 + qa1 + (double)b_in[hq * DH + lane];

        const float* wk = w_in + (size_t)(CC + hq * DH + lane) * CC;
        const double kbias = (double)b_in[CC + hq * DH + lane];
        double myS = -1.0e300;
        int myI = (1 << 30);
#pragma unroll 1
        for (int t = 0; t < C2; ++t) {
            int jt = __shfl(cand, t);
            const float* xk = x + ((size_t)bq * NN + jt) * CC;
            double ka0 = 0.0, ka1 = 0.0;
            for (int c = 0; c < CC; c += 8) {
                float4 a = *(const float4*)&xk[c];
                float4 b4 = *(const float4*)&wk[c];
                float4 a2 = *(const float4*)&xk[c + 4];
                float4 b2 = *(const float4*)&wk[c + 4];
                ka0 = fma((double)a.x, (double)b4.x, ka0);
                ka0 = fma((double)a.y, (double)b4.y, ka0);
                ka0 = fma((double)a.z, (double)b4.z, ka0);
                ka0 = fma((double)a.w, (double)b4.w, ka0);
                ka1 = fma((double)a2.x, (double)b2.x, ka1);
                ka1 = fma((double)a2.y, (double)b2.y, ka1);
                ka1 = fma((double)a2.z, (double)b2.z, ka1);
                ka1 = fma((double)a2.w, (double)b2.w, ka1);
            }
            double kd = ka0 + ka1 + kbias;
            double pr = qd * kd;                       // lane d's term of the score dot
#pragma unroll
            for (int off = 32; off; off >>= 1) pr += __shfl_xor(pr, off);
            if (lane == t) { myS = pr * 0.125; myI = jt; }
        }

        // exact fp64 top-16 among C2 (tie -> lower index); rank t lands on lane t
        double sS = myS;
        int sI = myI;
        double selS = 0.0;
#pragma unroll 1
        for (int t = 0; t < KTOP; ++t) {
            double bv = sS; int bi = sI;
#pragma unroll
            for (int off = 32; off; off >>= 1) {
                double ov = __shfl_xor(bv, off);
                int oi = __shfl_xor(bi, off);
                if (ov > bv || (ov == bv && oi < bi)) { bv = ov; bi = oi; }
            }
            if (lane == t) { selS = bv; selIdx = bi; }
            if (sI == bi) sS = -1.0e300;
        }

        double m = __shfl(selS, 0);
        float e = (lane < KTOP) ? expf((float)(selS - m)) : 0.0f;
        float sum = e;
#pragma unroll
        for (int off = 32; off; off >>= 1) sum += __shfl_xor(sum, off);
        p = e / sum;
    }

    // ---- shared tail: AV, zero-fill row, scatter probs, write xatt ----
    const float* vb = v32 + (size_t)bh * NN * DH;
    float o = 0.0f;
#pragma unroll
    for (int t = 0; t < KTOP; ++t) {
        int jt = __shfl(selIdx, t);
        float pt = __shfl(p, t);
        o = fmaf(pt, vb[(size_t)jt * DH + lane], o);
    }

#pragma unroll
    for (int i = 0; i < 4; ++i) {
        float4 z = make_float4(0.f, 0.f, 0.f, 0.f);
        *(float4*)&srow[i * 256 + lane * 4] = z;
    }
    asm volatile("s_waitcnt vmcnt(0)" ::: "memory");
    if (lane < KTOP) srow[selIdx] = p;

    int b = bh / HH, h = bh - b * HH;
    xatt[((size_t)b * NN + qn) * CC + h * DH + lane] = o;
}

// ---------------- Kernel 3: output projection (fp32) ----------------
__global__ __launch_bounds__(256) void out_proj(
    const float* __restrict__ a, const float* __restrict__ w,
    const float* __restrict__ bias, float* __restrict__ out) {
    __shared__ float a_lds[64][17];
    __shared__ float b_lds[64][17];
    const int tid = threadIdx.x;
    const int m0 = blockIdx.x * 64, n0 = blockIdx.y * 64;
    const int ty = tid >> 4, tx = tid & 15;
    const int lr = tid >> 2, lc = (tid & 3) << 2;

    float acc[4][4];
#pragma unroll
    for (int i = 0; i < 4; ++i)
#pragma unroll
        for (int j = 0; j < 4; ++j) acc[i][j] = 0.0f;

    for (int k0 = 0; k0 < CC; k0 += 16) {
        float4 av = *reinterpret_cast<const float4*>(&a[(size_t)(m0 + lr) * CC + k0 + lc]);
        float4 wv = *reinterpret_cast<const float4*>(&w[(size_t)(n0 + lr) * CC + k0 + lc]);
        __syncthreads();
        a_lds[lr][lc + 0] = av.x; a_lds[lr][lc + 1] = av.y;
        a_lds[lr][lc + 2] = av.z; a_lds[lr][lc + 3] = av.w;
        b_lds[lr][lc + 0] = wv.x; b_lds[lr][lc + 1] = wv.y;
        b_lds[lr][lc + 2] = wv.z; b_lds[lr][lc + 3] = wv.w;
        __syncthreads();
#pragma unroll
        for (int kk = 0; kk < 16; ++kk) {
            float a0 = a_lds[ty + 0][kk];
            float a1 = a_lds[ty + 16][kk];
            float a2 = a_lds[ty + 32][kk];
            float a3 = a_lds[ty + 48][kk];
            float w0 = b_lds[tx + 0][kk];
            float w1 = b_lds[tx + 16][kk];
            float w2 = b_lds[tx + 32][kk];
            float w3 = b_lds[tx + 48][kk];
            acc[0][0] = fmaf(a0, w0, acc[0][0]); acc[0][1] = fmaf(a0, w1, acc[0][1]);
            acc[0][2] = fmaf(a0, w2, acc[0][2]); acc[0][3] = fmaf(a0, w3, acc[0][3]);
            acc[1][0] = fmaf(a1, w0, acc[1][0]); acc[1][1] = fmaf(a1, w1, acc[1][1]);
            acc[1][2] = fmaf(a1, w2, acc[1][2]); acc[1][3] = fmaf(a1, w3, acc[1][3]);
            acc[2][0] = fmaf(a2, w0, acc[2][0]); acc[2][1] = fmaf(a2, w1, acc[2][1]);
            acc[2][2] = fmaf(a2, w2, acc[2][2]); acc[2][3] = fmaf(a2, w3, acc[2][3]);
            acc[3][0] = fmaf(a3, w0, acc[3][0]); acc[3][1] = fmaf(a3, w1, acc[3][1]);
            acc[3][2] = fmaf(a3, w2, acc[3][2]); acc[3][3] = fmaf(a3, w3, acc[3][3]);
        }
    }

#pragma unroll
    for (int i = 0; i < 4; ++i) {
#pragma unroll
        for (int j = 0; j < 4; ++j) {
            int m = m0 + ty + i * 16;
            int n = n0 + tx + j * 16;
            out[(size_t)m * CC + n] = acc[i][j] + bias[n];
        }
    }
}

extern "C" void kernel_launch(void* const* d_in, const int* in_sizes, int n_in,
                              void* d_out, int out_size, void* d_ws, size_t ws_size,
                              hipStream_t stream) {
    const float* x     = (const float*)d_in[0];
    const float* w_in  = (const float*)d_in[1];
    const float* b_in  = (const float*)d_in[2];
    const float* w_out = (const float*)d_in[3];
    const float* b_out = (const float*)d_in[4];

    float* xout     = (float*)d_out;                        // [B][N][C]
    float* attn_out = (float*)d_out + (size_t)BB * NN * CC; // [B][H][N][N]

    char* ws = (char*)d_ws;
    float* q32  = (float*)ws;                               // 12,582,912 B
    float* k32  = (float*)(ws + 12582912);                  // 12,582,912 B
    float* v32  = (float*)(ws + 25165824);                  // 12,582,912 B
    float* xatt = (float*)(ws + 37748736);                  // 12,582,912 B

    hipLaunchKernelGGL(qkv_proj32, dim3(64, 36), dim3(256), 0, stream,
                       x, w_in, b_in, q32, k32, v32);
    hipLaunchKernelGGL(scores32, dim3(NN / 64, BB * HH), dim3(256), 0, stream,
                       q32, k32, attn_out);
    hipLaunchKernelGGL(topk_select, dim3(BB * HH * (NN / 4)), dim3(256), 0, stream,
                       x, w_in, b_in, v32, attn_out, xatt);
    hipLaunchKernelGGL(out_proj, dim3(64, 12), dim3(256), 0, stream,
                       xatt, w_out, b_out, xout);
}

// Round 9
// 879.103 us; speedup vs baseline: 1.8612x; 1.8612x over previous
//
#include <hip/hip_runtime.h>
#include <math.h>
#include <stdint.h>

#define BB 4
#define NN 1024
#define CC 768
#define HH 12
#define DH 64
#define KTOP 16

// ---------------- Kernel 1: fused QKV projection (fp32) ----------------
__global__ __launch_bounds__(256) void qkv_proj32(
    const float* __restrict__ x, const float* __restrict__ w,
    const float* __restrict__ bias,
    float* __restrict__ q32, float* __restrict__ k32, float* __restrict__ v32) {
    __shared__ float a_lds[64][17];
    __shared__ float b_lds[64][17];
    const int tid = threadIdx.x;
    const int m0 = blockIdx.x * 64, n0 = blockIdx.y * 64;   // n0 in [0,2304)
    const int ty = tid >> 4, tx = tid & 15;
    const int lr = tid >> 2, lc = (tid & 3) << 2;

    float acc[4][4];
#pragma unroll
    for (int i = 0; i < 4; ++i)
#pragma unroll
        for (int j = 0; j < 4; ++j) acc[i][j] = 0.0f;

    for (int k0 = 0; k0 < CC; k0 += 16) {
        float4 av = *reinterpret_cast<const float4*>(&x[(size_t)(m0 + lr) * CC + k0 + lc]);
        float4 wv = *reinterpret_cast<const float4*>(&w[(size_t)(n0 + lr) * CC + k0 + lc]);
        __syncthreads();
        a_lds[lr][lc + 0] = av.x; a_lds[lr][lc + 1] = av.y;
        a_lds[lr][lc + 2] = av.z; a_lds[lr][lc + 3] = av.w;
        b_lds[lr][lc + 0] = wv.x; b_lds[lr][lc + 1] = wv.y;
        b_lds[lr][lc + 2] = wv.z; b_lds[lr][lc + 3] = wv.w;
        __syncthreads();
#pragma unroll
        for (int kk = 0; kk < 16; ++kk) {
            float a0 = a_lds[ty + 0][kk];
            float a1 = a_lds[ty + 16][kk];
            float a2 = a_lds[ty + 32][kk];
            float a3 = a_lds[ty + 48][kk];
            float w0 = b_lds[tx + 0][kk];
            float w1 = b_lds[tx + 16][kk];
            float w2 = b_lds[tx + 32][kk];
            float w3 = b_lds[tx + 48][kk];
            acc[0][0] = fmaf(a0, w0, acc[0][0]); acc[0][1] = fmaf(a0, w1, acc[0][1]);
            acc[0][2] = fmaf(a0, w2, acc[0][2]); acc[0][3] = fmaf(a0, w3, acc[0][3]);
            acc[1][0] = fmaf(a1, w0, acc[1][0]); acc[1][1] = fmaf(a1, w1, acc[1][1]);
            acc[1][2] = fmaf(a1, w2, acc[1][2]); acc[1][3] = fmaf(a1, w3, acc[1][3]);
            acc[2][0] = fmaf(a2, w0, acc[2][0]); acc[2][1] = fmaf(a2, w1, acc[2][1]);
            acc[2][2] = fmaf(a2, w2, acc[2][2]); acc[2][3] = fmaf(a2, w3, acc[2][3]);
            acc[3][0] = fmaf(a3, w0, acc[3][0]); acc[3][1] = fmaf(a3, w1, acc[3][1]);
            acc[3][2] = fmaf(a3, w2, acc[3][2]); acc[3][3] = fmaf(a3, w3, acc[3][3]);
        }
    }

#pragma unroll
    for (int i = 0; i < 4; ++i) {
#pragma unroll
        for (int j = 0; j < 4; ++j) {
            int m = m0 + ty + i * 16;
            int col = n0 + tx + j * 16;              // [0,2304)
            float val = acc[i][j] + bias[col];
            int t = col / CC;
            int rem = col - t * CC;
            int h = rem >> 6, d = rem & 63;
            int b = m >> 10, n = m & 1023;
            size_t off = (((size_t)(b * HH + h)) * NN + n) * DH + d;
            if (t == 0) q32[off] = val;
            else if (t == 1) k32[off] = val;
            else v32[off] = val;
        }
    }
}

// ---------------- Kernel 2a: fp32 scores GEMM (64-row blocks) ----------------
__global__ __launch_bounds__(256) void scores32(
    const float* __restrict__ q32, const float* __restrict__ k32,
    float* __restrict__ attn_out) {
    __shared__ float qs[64][64];
    __shared__ float ks[128][64];
    const int bh = blockIdx.y;
    const int m0 = blockIdx.x * 64;
    const int tid = threadIdx.x;
    const int ty = tid >> 4, tx = tid & 15;

    const float* qb = q32 + ((size_t)bh * NN + m0) * DH;
    const float* kb = k32 + (size_t)bh * NN * DH;

#pragma unroll
    for (int wv = 0; wv < 4; ++wv) {
        int e = tid + 256 * wv;
        int row = e >> 4, d4 = e & 15;
        float4 f = *reinterpret_cast<const float4*>(&qb[(size_t)row * DH + d4 * 4]);
        f.x *= 0.125f; f.y *= 0.125f; f.z *= 0.125f; f.w *= 0.125f;
        ((float4*)qs[row])[d4 ^ (row >> 3)] = f;
    }

    float* orow0 = attn_out + ((size_t)bh * NN + m0) * NN;

    for (int c0 = 0; c0 < NN; c0 += 128) {
        __syncthreads();
#pragma unroll
        for (int wv = 0; wv < 8; ++wv) {
            int e = tid + 256 * wv;
            int col = e >> 4, d4 = e & 15;
            float4 f = *reinterpret_cast<const float4*>(&kb[(size_t)(c0 + col) * DH + d4 * 4]);
            ((float4*)ks[col])[d4 ^ ((col >> 3) & 15)] = f;
        }
        __syncthreads();

        float acc[4][8];
#pragma unroll
        for (int i = 0; i < 4; ++i)
#pragma unroll
            for (int j = 0; j < 8; ++j) acc[i][j] = 0.0f;

#pragma unroll
        for (int d4 = 0; d4 < 16; ++d4) {
            float4 a4[4];
#pragma unroll
            for (int i = 0; i < 4; ++i)
                a4[i] = ((float4*)qs[4 * ty + i])[d4 ^ ((4 * ty + i) >> 3)];
#pragma unroll
            for (int j = 0; j < 8; ++j) {
                float4 b4 = ((float4*)ks[8 * tx + j])[d4 ^ tx];
#pragma unroll
                for (int i = 0; i < 4; ++i) {
                    acc[i][j] = fmaf(a4[i].x, b4.x, acc[i][j]);
                    acc[i][j] = fmaf(a4[i].y, b4.y, acc[i][j]);
                    acc[i][j] = fmaf(a4[i].z, b4.z, acc[i][j]);
                    acc[i][j] = fmaf(a4[i].w, b4.w, acc[i][j]);
                }
            }
        }

#pragma unroll
        for (int i = 0; i < 4; ++i) {
#pragma unroll
            for (int jj = 0; jj < 2; ++jj) {
                float4 o;
                o.x = acc[i][4 * jj + 0]; o.y = acc[i][4 * jj + 1];
                o.z = acc[i][4 * jj + 2]; o.w = acc[i][4 * jj + 3];
                *(float4*)&orow0[(size_t)(4 * ty + i) * NN + c0 + 8 * tx + 4 * jj] = o;
            }
        }
    }
}

// ---------------- Kernel 2b: bitonic top-16; slow rows -> worklist ----------------
__device__ __forceinline__ uint32_t f2su(float f) {
    uint32_t u = __float_as_uint(f);
    return u ^ ((u & 0x80000000u) ? 0xFFFFFFFFu : 0x80000000u);
}
__device__ __forceinline__ float su2f(uint32_t s) {
    uint32_t u = s ^ ((s & 0x80000000u) ? 0x80000000u : 0xFFFFFFFFu);
    return __uint_as_float(u);
}

__global__ __launch_bounds__(256) void topk_select(
    const float* __restrict__ v32,
    float* __restrict__ attn_out, float* __restrict__ xatt,
    int* __restrict__ wl_count, int* __restrict__ wl_row, int* __restrict__ wl_cand) {
    __shared__ int      cand_idx[4][64];
    __shared__ uint32_t cand_val[4][64];
    const int blk = blockIdx.x;
    const int wave = threadIdx.x >> 6, lane = threadIdx.x & 63;
    const int bh = blk >> 8;
    const int qn = ((blk & 255) << 2) | wave;

    float* srow = attn_out + ((size_t)bh * NN + qn) * NN;

    uint32_t su[16];
#pragma unroll
    for (int i = 0; i < 4; ++i) {
        float4 t = *(const float4*)&srow[i * 256 + lane * 4];
        su[4 * i + 0] = f2su(t.x); su[4 * i + 1] = f2su(t.y);
        su[4 * i + 2] = f2su(t.z); su[4 * i + 3] = f2su(t.w);
    }

    // binary search: largest thr with count(su >= thr) >= 17; early-exit in [17,64]
    uint32_t thr = 0;
    for (int b = 31; b >= 0; --b) {
        uint32_t test = thr | (1u << b);
        int cnt = 0;
#pragma unroll
        for (int r = 0; r < 16; ++r)
            cnt += __popcll(__ballot(su[r] >= test));
        if (cnt >= 17) { thr = test; if (cnt <= 64) break; }
    }

    int C = 0;
#pragma unroll
    for (int r = 0; r < 16; ++r) {
        bool pr = (su[r] >= thr);
        unsigned long long mask = __ballot(pr);
        if (pr) {
            int pos = C + __popcll(mask & ((1ull << lane) - 1ull));
            if (pos < 64) {
                cand_idx[wave][pos] = ((r >> 2) << 8) + (lane << 2) + (r & 3);
                cand_val[wave][pos] = su[r];
            }
        }
        C += __popcll(mask);
    }
    if (C > 64) C = 64;

    uint32_t key = (lane < C) ? cand_val[wave][lane] : 0u;
    int      idx = (lane < C) ? cand_idx[wave][lane] : (0x40000000 + lane);

    // bitonic sort 64 lanes: (key desc, idx asc)
#pragma unroll
    for (int k = 2; k <= 64; k <<= 1) {
#pragma unroll
        for (int j = k >> 1; j > 0; j >>= 1) {
            uint32_t ok = __shfl_xor(key, j);
            int      oi = __shfl_xor(idx, j);
            bool mine_better = (key > ok) || (key == ok && idx < oi);
            bool lower = ((lane & j) == 0);
            bool dir_desc = ((lane & k) == 0);
            bool keep = dir_desc ? (lower ? mine_better : !mine_better)
                                 : (lower ? !mine_better : mine_better);
            if (!keep) { key = ok; idx = oi; }
        }
    }

    float f = su2f(key);
    float f15 = __shfl(f, 15);
    float f16 = __shfl(f, 16);

    bool fast = (f15 - f16 > 2e-4f);
    float p = 0.0f;
    int selIdx = idx;

    if (fast) {
        float m = __shfl(f, 0);
        float e = (lane < KTOP) ? expf(f - m) : 0.0f;
        float sum = e;
#pragma unroll
        for (int off = 32; off; off >>= 1) sum += __shfl_xor(sum, off);
        p = e / sum;
    } else {
        // recompact with superset threshold, append to worklist
        uint32_t thr2 = f2su(f15 - 4e-4f);
        int C2 = 0;
#pragma unroll
        for (int r = 0; r < 16; ++r) {
            bool pr = (su[r] >= thr2);
            unsigned long long mask = __ballot(pr);
            if (pr) {
                int pos = C2 + __popcll(mask & ((1ull << lane) - 1ull));
                if (pos < 64) cand_idx[wave][pos] = ((r >> 2) << 8) + (lane << 2) + (r & 3);
            }
            C2 += __popcll(mask);
        }
        if (C2 > 64) C2 = 64;

        int slot = 0;
        if (lane == 0) slot = atomicAdd(wl_count, 1);
        slot = __shfl(slot, 0);
        int rowid = (bh << 10) | qn;
        if (lane == 0) wl_row[slot] = rowid | (C2 << 20);
        if (lane < C2) wl_cand[(size_t)slot * 64 + lane] = cand_idx[wave][lane];
    }

    // zero-fill row (all rows); fast rows also AV+scatter+xatt
#pragma unroll
    for (int i = 0; i < 4; ++i) {
        float4 z = make_float4(0.f, 0.f, 0.f, 0.f);
        *(float4*)&srow[i * 256 + lane * 4] = z;
    }

    if (fast) {
        const float* vb = v32 + (size_t)bh * NN * DH;
        float o = 0.0f;
#pragma unroll
        for (int t = 0; t < KTOP; ++t) {
            int jt = __shfl(selIdx, t);
            float pt = __shfl(p, t);
            o = fmaf(pt, vb[(size_t)jt * DH + lane], o);
        }
        asm volatile("s_waitcnt vmcnt(0)" ::: "memory");
        if (lane < KTOP) srow[selIdx] = p;
        int b = bh / HH, h = bh - b * HH;
        xatt[((size_t)b * NN + qn) * CC + h * DH + lane] = o;
    }
}

// ---------------- Kernel 2c: slow rows — exact fp64 rescore, coalesced cooperative ----------
__global__ __launch_bounds__(64) void slow_rescore(
    const float* __restrict__ x, const float* __restrict__ w_in,
    const float* __restrict__ b_in, const float* __restrict__ v32,
    const int* __restrict__ wl_count, const int* __restrict__ wl_row,
    const int* __restrict__ wl_cand,
    float* __restrict__ attn_out, float* __restrict__ xatt) {
    __shared__ double part[64][65];     // padded: lane-stride read = 4-way alias max
    const int lane = threadIdx.x;
    const int count = wl_count[0];

    for (int it = blockIdx.x; it < count; it += gridDim.x) {
        int ent = wl_row[it];
        int rowid = ent & 0xFFFF;
        int C2 = (ent >> 20) & 0x7F;
        int bh = rowid >> 10, qn = rowid & 1023;
        int bq = bh / HH, hq = bh - bq * HH;

        // stage x_q (fp64 regs; lane l owns cols {4l,256+4l,512+4l}+0..3)
        const float* xq = x + ((size_t)bq * NN + qn) * CC;
        double xqd[12];
#pragma unroll
        for (int c = 0; c < 3; ++c) {
            float4 v = *(const float4*)&xq[c * 256 + 4 * lane];
            xqd[4 * c + 0] = v.x; xqd[4 * c + 1] = v.y;
            xqd[4 * c + 2] = v.z; xqd[4 * c + 3] = v.w;
        }

        // q64 = W_q(head) · x_q  — coalesced row sweep, LDS transpose-reduce
        const float* wqb = w_in + (size_t)(hq * DH) * CC;
        for (int r = 0; r < 64; ++r) {
            const float* wr = wqb + (size_t)r * CC;
            double s = 0.0;
#pragma unroll
            for (int c = 0; c < 3; ++c) {
                float4 v = *(const float4*)&wr[c * 256 + 4 * lane];
                s = fma((double)v.x, xqd[4 * c + 0], s);
                s = fma((double)v.y, xqd[4 * c + 1], s);
                s = fma((double)v.z, xqd[4 * c + 2], s);
                s = fma((double)v.w, xqd[4 * c + 3], s);
            }
            part[r][lane] = s;
        }
        __syncthreads();
        double q64 = 0.0, q64b = 0.0;
#pragma unroll
        for (int l = 0; l < 64; l += 2) { q64 += part[lane][l]; q64b += part[lane][l + 1]; }
        q64 += q64b + (double)b_in[hq * DH + lane];
        __syncthreads();

        const float* wkb = w_in + (size_t)(CC + hq * DH) * CC;
        const double kbias = (double)b_in[CC + hq * DH + lane];

        double myS = -1.0e300;
        int myI = (1 << 30);
        for (int t = 0; t < C2; ++t) {
            int jt = wl_cand[(size_t)it * 64 + t];
            const float* xk = x + ((size_t)bq * NN + jt) * CC;
            double xkd[12];
#pragma unroll
            for (int c = 0; c < 3; ++c) {
                float4 v = *(const float4*)&xk[c * 256 + 4 * lane];
                xkd[4 * c + 0] = v.x; xkd[4 * c + 1] = v.y;
                xkd[4 * c + 2] = v.z; xkd[4 * c + 3] = v.w;
            }
            for (int r = 0; r < 64; ++r) {
                const float* wr = wkb + (size_t)r * CC;
                double s = 0.0;
#pragma unroll
                for (int c = 0; c < 3; ++c) {
                    float4 v = *(const float4*)&wr[c * 256 + 4 * lane];
                    s = fma((double)v.x, xkd[4 * c + 0], s);
                    s = fma((double)v.y, xkd[4 * c + 1], s);
                    s = fma((double)v.z, xkd[4 * c + 2], s);
                    s = fma((double)v.w, xkd[4 * c + 3], s);
                }
                part[r][lane] = s;
            }
            __syncthreads();
            double k64 = 0.0, k64b = 0.0;
#pragma unroll
            for (int l = 0; l < 64; l += 2) { k64 += part[lane][l]; k64b += part[lane][l + 1]; }
            k64 += k64b + kbias;
            double pr = q64 * k64;
#pragma unroll
            for (int off = 32; off; off >>= 1) pr += __shfl_xor(pr, off);
            if (lane == t) { myS = pr * 0.125; myI = jt; }
            __syncthreads();
        }

        // exact fp64 top-16 among C2 (tie -> lower index)
        double sS = myS;
        int sI = myI;
        double selS = 0.0; int selIdx = 0;
#pragma unroll 1
        for (int t = 0; t < KTOP; ++t) {
            double bv = sS; int bi = sI;
#pragma unroll
            for (int off = 32; off; off >>= 1) {
                double ov = __shfl_xor(bv, off);
                int oi = __shfl_xor(bi, off);
                if (ov > bv || (ov == bv && oi < bi)) { bv = ov; bi = oi; }
            }
            if (lane == t) { selS = bv; selIdx = bi; }
            if (sI == bi) sS = -1.0e300;
        }

        double m = __shfl(selS, 0);
        float e = (lane < KTOP) ? expf((float)(selS - m)) : 0.0f;
        float sum = e;
#pragma unroll
        for (int off = 32; off; off >>= 1) sum += __shfl_xor(sum, off);
        float p = e / sum;

        const float* vb = v32 + (size_t)bh * NN * DH;
        float o = 0.0f;
#pragma unroll
        for (int t = 0; t < KTOP; ++t) {
            int jt = __shfl(selIdx, t);
            float pt = __shfl(p, t);
            o = fmaf(pt, vb[(size_t)jt * DH + lane], o);
        }

        float* srow = attn_out + (size_t)rowid * NN;   // already zeroed by topk_select
        if (lane < KTOP) srow[selIdx] = p;
        xatt[((size_t)bq * NN + qn) * CC + hq * DH + lane] = o;
        __syncthreads();
    }
}

// ---------------- Kernel 3: output projection (fp32) ----------------
__global__ __launch_bounds__(256) void out_proj(
    const float* __restrict__ a, const float* __restrict__ w,
    const float* __restrict__ bias, float* __restrict__ out) {
    __shared__ float a_lds[64][17];
    __shared__ float b_lds[64][17];
    const int tid = threadIdx.x;
    const int m0 = blockIdx.x * 64, n0 = blockIdx.y * 64;
    const int ty = tid >> 4, tx = tid & 15;
    const int lr = tid >> 2, lc = (tid & 3) << 2;

    float acc[4][4];
#pragma unroll
    for (int i = 0; i < 4; ++i)
#pragma unroll
        for (int j = 0; j < 4; ++j) acc[i][j] = 0.0f;

    for (int k0 = 0; k0 < CC; k0 += 16) {
        float4 av = *reinterpret_cast<const float4*>(&a[(size_t)(m0 + lr) * CC + k0 + lc]);
        float4 wv = *reinterpret_cast<const float4*>(&w[(size_t)(n0 + lr) * CC + k0 + lc]);
        __syncthreads();
        a_lds[lr][lc + 0] = av.x; a_lds[lr][lc + 1] = av.y;
        a_lds[lr][lc + 2] = av.z; a_lds[lr][lc + 3] = av.w;
        b_lds[lr][lc + 0] = wv.x; b_lds[lr][lc + 1] = wv.y;
        b_lds[lr][lc + 2] = wv.z; b_lds[lr][lc + 3] = wv.w;
        __syncthreads();
#pragma unroll
        for (int kk = 0; kk < 16; ++kk) {
            float a0 = a_lds[ty + 0][kk];
            float a1 = a_lds[ty + 16][kk];
            float a2 = a_lds[ty + 32][kk];
            float a3 = a_lds[ty + 48][kk];
            float w0 = b_lds[tx + 0][kk];
            float w1 = b_lds[tx + 16][kk];
            float w2 = b_lds[tx + 32][kk];
            float w3 = b_lds[tx + 48][kk];
            acc[0][0] = fmaf(a0, w0, acc[0][0]); acc[0][1] = fmaf(a0, w1, acc[0][1]);
            acc[0][2] = fmaf(a0, w2, acc[0][2]); acc[0][3] = fmaf(a0, w3, acc[0][3]);
            acc[1][0] = fmaf(a1, w0, acc[1][0]); acc[1][1] = fmaf(a1, w1, acc[1][1]);
            acc[1][2] = fmaf(a1, w2, acc[1][2]); acc[1][3] = fmaf(a1, w3, acc[1][3]);
            acc[2][0] = fmaf(a2, w0, acc[2][0]); acc[2][1] = fmaf(a2, w1, acc[2][1]);
            acc[2][2] = fmaf(a2, w2, acc[2][2]); acc[2][3] = fmaf(a2, w3, acc[2][3]);
            acc[3][0] = fmaf(a3, w0, acc[3][0]); acc[3][1] = fmaf(a3, w1, acc[3][1]);
            acc[3][2] = fmaf(a3, w2, acc[3][2]); acc[3][3] = fmaf(a3, w3, acc[3][3]);
        }
    }

#pragma unroll
    for (int i = 0; i < 4; ++i) {
#pragma unroll
        for (int j = 0; j < 4; ++j) {
            int m = m0 + ty + i * 16;
            int n = n0 + tx + j * 16;
            out[(size_t)m * CC + n] = acc[i][j] + bias[n];
        }
    }
}

extern "C" void kernel_launch(void* const* d_in, const int* in_sizes, int n_in,
                              void* d_out, int out_size, void* d_ws, size_t ws_size,
                              hipStream_t stream) {
    const float* x     = (const float*)d_in[0];
    const float* w_in  = (const float*)d_in[1];
    const float* b_in  = (const float*)d_in[2];
    const float* w_out = (const float*)d_in[3];
    const float* b_out = (const float*)d_in[4];

    float* xout     = (float*)d_out;                        // [B][N][C]
    float* attn_out = (float*)d_out + (size_t)BB * NN * CC; // [B][H][N][N]

    char* ws = (char*)d_ws;
    float* q32     = (float*)ws;                            // 12,582,912 B
    float* k32     = (float*)(ws + 12582912);               // 12,582,912 B
    float* v32     = (float*)(ws + 25165824);               // 12,582,912 B
    float* xatt    = (float*)(ws + 37748736);               // 12,582,912 B
    int*   wl_count = (int*)(ws + 50331648);                // 4 B (pad 256)
    int*   wl_row   = (int*)(ws + 50331904);                // 196,608 B
    int*   wl_cand  = (int*)(ws + 50528512);                // 12,582,912 B

    hipMemsetAsync(wl_count, 0, sizeof(int), stream);

    hipLaunchKernelGGL(qkv_proj32, dim3(64, 36), dim3(256), 0, stream,
                       x, w_in, b_in, q32, k32, v32);
    hipLaunchKernelGGL(scores32, dim3(NN / 64, BB * HH), dim3(256), 0, stream,
                       q32, k32, attn_out);
    hipLaunchKernelGGL(topk_select, dim3(BB * HH * (NN / 4)), dim3(256), 0, stream,
                       v32, attn_out, xatt, wl_count, wl_row, wl_cand);
    hipLaunchKernelGGL(slow_rescore, dim3(1024), dim3(64), 0, stream,
                       x, w_in, b_in, v32, wl_count, wl_row, wl_cand, attn_out, xatt);
    hipLaunchKernelGGL(out_proj, dim3(64, 12), dim3(256), 0, stream,
                       xatt, w_out, b_out, xout);
}